// Round 8
// baseline (1013.088 us; speedup 1.0000x reference)
//
#include <hip/hip_runtime.h>
#include <math.h>

static constexpr int HEADS  = 8;
static constexpr int DHEAD  = 96;
static constexpr int INNER  = 768;
static constexpr int NPEP   = 128;
static constexpr int MPRO   = 2048;
static constexpr float ATT_SCALE = 0.10206207261596577f;  // 96^-0.5
static constexpr float NEGF   = -1000000.0f;
static constexpr float LN_EPS = 1e-5f;

typedef __attribute__((ext_vector_type(8))) short bf16x8;
typedef __attribute__((ext_vector_type(4))) float f32x4;

__device__ __forceinline__ unsigned short f2b(float f) {
    unsigned u = __builtin_bit_cast(unsigned, f);
    u += 0x7fffu + ((u >> 16) & 1u);          // RNE
    return (unsigned short)(u >> 16);
}
__device__ __forceinline__ float b2f(unsigned short u) {
    return __builtin_bit_cast(float, (unsigned)u << 16);
}

// ---------------------------------------------------------------------------
// Direct-global bf16 MFMA GEMM (B^T form): C[row,col] = sum_k A[row,k]*B[col,k]
// NO LDS, NO barriers, NO staging: each wave loads its MFMA fragments
// straight from global (L2-hot operands; the fusedpv-PV1-proven pattern:
// 16 rows x 16B per fragment). 1-deep register prefetch via two named
// fragment sets + even/odd unrolled loop (all indexing compile-time).
// R7 post-mortem: every LDS-staged variant (7 ablations) pinned at ~20%
// MfmaUtil = MFMA cycles / (ds_read+stage+barrier serial chain). This
// removes the chain entirely; occupancy is VGPR-bound only (LDS=0).
// MODE 1: scores: v*SCALE -> bf16, batched via z (strides).
// MODE 2: row-major bf16 out (col<N guard).
// MODE 3/4 layouts via MODE 5: merged dual projection (virtual N=1536):
//   n0<768 -> B->C head-split (b,h,len,96); else B2->C2 (b,h,96,len).
// nx > 0: 1-D grid, XCD-chunked bijective swizzle (grid%8==0), nx col-tiles.
// ---------------------------------------------------------------------------
template<int TM, int MODE>
__global__ __launch_bounds__(256) void gemm_dg(
    const unsigned short* __restrict__ A, const unsigned short* __restrict__ B,
    unsigned short* __restrict__ C,
    int N, int K, int lda, int ldb, int ldc,
    long sAb, long sAh, long sBb, long sBh, long sCb, long sCh,
    int lenShift, int nx,
    const unsigned short* __restrict__ B2, unsigned short* __restrict__ C2)
{
    constexpr int FR = TM / 32;                 // row-fragments per wave
    const int tid = threadIdx.x;
    int bx, by;
    if (nx > 0) {
        const int bid = blockIdx.x;
        const int per = gridDim.x >> 3;          // grid % 8 == 0 (bijective)
        const int v   = (bid & 7) * per + (bid >> 3);
        bx = v % nx; by = v / nx;
    } else { bx = blockIdx.x; by = blockIdx.y; }
    int n0        = bx * 128;
    const int m0  = by * TM;
    const int z   = blockIdx.z;
    const int zb  = z >> 3, zh = z & 7;

    bool sideB = false;
    if (MODE == 5 && n0 >= 768) { sideB = true; n0 -= 768; }

    const unsigned short* Ab = A + zb * sAb + zh * sAh;
    const unsigned short* Bb = ((MODE == 5 && sideB) ? B2 : B) + zb * sBb + zh * sBh;

    const int wave = tid >> 6;
    const int lane = tid & 63;
    const int l16  = lane & 15;
    const int quad = lane >> 4;
    const int wr   = (wave >> 1) * (TM / 2);
    const int wc   = (wave & 1) * 64;

    // per-fragment base pointers; K advances by +64 B per step (imm-offset friendly)
    const unsigned short* pA[FR];
    const unsigned short* pB[4];
#pragma unroll
    for (int i = 0; i < FR; ++i)
        pA[i] = Ab + (long)(m0 + wr + i * 16 + l16) * lda + quad * 8;
#pragma unroll
    for (int j = 0; j < 4; ++j) {
        int br = n0 + wc + j * 16 + l16; if (br > N - 1) br = N - 1;
        pB[j] = Bb + (long)br * ldb + quad * 8;
    }

    f32x4 acc[FR][4];
#pragma unroll
    for (int i = 0; i < FR; ++i)
#pragma unroll
        for (int j = 0; j < 4; ++j) acc[i][j] = (f32x4){0.f, 0.f, 0.f, 0.f};

    bf16x8 afA[FR], bfA[4], afB[FR], bfB[4];

    auto LOAD = [&](bf16x8* af, bf16x8* bf, int t) {
        const int k = t * 32;
#pragma unroll
        for (int i = 0; i < FR; ++i)
            af[i] = *reinterpret_cast<const bf16x8*>(pA[i] + k);
#pragma unroll
        for (int j = 0; j < 4; ++j)
            bf[j] = *reinterpret_cast<const bf16x8*>(pB[j] + k);
    };
    auto STEP = [&](const bf16x8* af, const bf16x8* bf) {
#pragma unroll
        for (int i = 0; i < FR; ++i)
#pragma unroll
            for (int j = 0; j < 4; ++j)
                acc[i][j] = __builtin_amdgcn_mfma_f32_16x16x32_bf16(af[i], bf[j], acc[i][j], 0, 0, 0);
    };

    const int NT = K >> 5;                      // K-step 32
    LOAD(afA, bfA, 0);
    int t = 0;
    for (; t + 2 <= NT; t += 2) {
        if (t + 1 < NT) LOAD(afB, bfB, t + 1);  // prefetch under STEP(afA)
        STEP(afA, bfA);
        if (t + 2 < NT) LOAD(afA, bfA, t + 2);  // prefetch under STEP(afB)
        STEP(afB, bfB);
    }
    if (t < NT) STEP(afA, bfA);                 // odd-NT tail (tile t in afA)

#pragma unroll
    for (int i = 0; i < FR; ++i) {
#pragma unroll
        for (int j = 0; j < 4; ++j) {
            const int col = n0 + wc + j * 16 + l16;
            if ((MODE == 2) && col >= N) continue;
            const int h = col / 96, d = col - h * 96;   // MODE 5 layouts
#pragma unroll
            for (int r = 0; r < 4; ++r) {
                const int row = m0 + wr + i * 16 + quad * 4 + r;
                float v = acc[i][j][r];
                if (MODE == 1) {
                    v *= ATT_SCALE;
                    C[zb * sCb + zh * sCh + (long)row * ldc + col] = f2b(v);
                } else if (MODE == 2) {
                    C[zb * sCb + zh * sCh + (long)row * ldc + col] = f2b(v);
                } else { // MODE 5
                    const int bb = row >> lenShift, rr = row & ((1 << lenShift) - 1);
                    if (!sideB)
                        C [(((long)(bb * 8 + h) << lenShift) + rr) * 96 + d] = f2b(v);
                    else
                        C2[(((long)(bb * 8 + h) * 96 + d) << lenShift) + rr] = f2b(v);
                }
            }
        }
    }
}

// ---------------------------------------------------------------------------
// Fused PV: one block per (z, nh) with z = b*8+h, nh in {0,1}; 256 blocks.
//   PV1: opp[b,n,h*96+d] = sum_m attn[z,n,m]*vpT[z,d,m]   (direct-global frags)
//   PV2: opep[b,m,h*96+d] = sum_n attn[z,n,m]*vpepT[z,d,n] (LDS transpose)
// ---------------------------------------------------------------------------
__global__ __launch_bounds__(256) void fusedpv_kernel(
    const unsigned short* __restrict__ attn16,  // (z,128,2048) bf16
    const unsigned short* __restrict__ vprotT,  // (z,96,2048)
    const unsigned short* __restrict__ vpepT,   // (z,96,128)
    unsigned short* __restrict__ opp,           // (b,128,768)
    unsigned short* __restrict__ opep)          // (b,2048,768)
{
    __shared__ unsigned short AttT[128 * 136];  // [m][n] for current chunk
    __shared__ unsigned short Vp[96 * 136];     // [d][n], resident

    const int id = blockIdx.x;
    const int z  = ((id >> 4) << 3) + (id & 7); // ids i, i+8 share z (same XCD)
    const int nh = (id >> 3) & 1;
    const int b  = z >> 3, h = z & 7;

    const unsigned short* Az = attn16 + (long)z * NPEP * MPRO;
    const unsigned short* Vz = vprotT + (long)z * 96 * MPRO;
    const unsigned short* Pz = vpepT  + (long)z * 96 * 128;

    const int tid  = threadIdx.x;
    const int lane = tid & 63;
    const int l16  = lane & 15;
    const int quad = lane >> 4;
    const int wave = tid >> 6;
    const int wrN  = (wave >> 1) * 32;   // PV1 row base within this block's 64
    const int wrM  = (wave >> 1) * 64;   // PV2 row base within 128-chunk
    const int wcD  = (wave & 1) * 48;    // d col base (2 waves x 48 = 96)

    // stage Vp[d][n] (96x128 -> pitch 136): 1536 8-elem chunks, 6/thread
#pragma unroll
    for (int e = 0; e < 6; ++e) {
        const int c = tid + e * 256;
        const int row = c >> 4, coloff = (c & 15) * 8;
        bf16x8 v = *reinterpret_cast<const bf16x8*>(Pz + row * 128 + coloff);
        *reinterpret_cast<bf16x8*>(&Vp[row * 136 + coloff]) = v;
    }
    __syncthreads();

    f32x4 acc1[2][3];
#pragma unroll
    for (int i = 0; i < 2; ++i)
#pragma unroll
        for (int j = 0; j < 3; ++j) acc1[i][j] = (f32x4){0.f, 0.f, 0.f, 0.f};

    for (int cc = 0; cc < 16; ++cc) {
        const int m0 = cc * 128;
        const bool own = (cc >> 3) == nh;        // block-uniform

        // PV1 fragment loads (direct global, issued first to hide latency)
        bf16x8 a1[2][4], b1[3][4];
#pragma unroll
        for (int i = 0; i < 2; ++i) {
            const int n = nh * 64 + wrN + i * 16 + l16;
#pragma unroll
            for (int kc = 0; kc < 4; ++kc)
                a1[i][kc] = *reinterpret_cast<const bf16x8*>(
                    Az + (long)n * MPRO + m0 + kc * 32 + quad * 8);
        }
#pragma unroll
        for (int j = 0; j < 3; ++j) {
            const int d = wcD + j * 16 + l16;
#pragma unroll
            for (int kc = 0; kc < 4; ++kc)
                b1[j][kc] = *reinterpret_cast<const bf16x8*>(
                    Vz + (long)d * MPRO + m0 + kc * 32 + quad * 8);
        }

        if (own) {
            // stage AttT[m][n] = Az[n][m0+m]
            const int mBase = (tid & 7) * 16;
#pragma unroll
            for (int nn = 0; nn < 128; nn += 32) {
                const int n = nn + (tid >> 3);
#pragma unroll
                for (int c = 0; c < 2; ++c) {
                    bf16x8 v = *reinterpret_cast<const bf16x8*>(
                        Az + (long)n * MPRO + m0 + mBase + c * 8);
#pragma unroll
                    for (int jj = 0; jj < 8; ++jj)
                        AttT[(mBase + c * 8 + jj) * 136 + n] = (unsigned short)v[jj];
                }
            }
            __syncthreads();
        }

        // PV1 MFMAs (accumulate across all 16 chunks)
#pragma unroll
        for (int kc = 0; kc < 4; ++kc)
#pragma unroll
            for (int i = 0; i < 2; ++i)
#pragma unroll
                for (int j = 0; j < 3; ++j)
                    acc1[i][j] = __builtin_amdgcn_mfma_f32_16x16x32_bf16(
                        a1[i][kc], b1[j][kc], acc1[i][j], 0, 0, 0);

        if (own) {
            // PV2 for this chunk: K = n = 128, fresh accumulator
            f32x4 acc2[4][3];
#pragma unroll
            for (int i = 0; i < 4; ++i)
#pragma unroll
                for (int j = 0; j < 3; ++j) acc2[i][j] = (f32x4){0.f, 0.f, 0.f, 0.f};
#pragma unroll
            for (int kc = 0; kc < 4; ++kc) {
                bf16x8 a2[4], b2v[3];
#pragma unroll
                for (int i = 0; i < 4; ++i)
                    a2[i] = *reinterpret_cast<const bf16x8*>(
                        &AttT[(wrM + i * 16 + l16) * 136 + kc * 32 + quad * 8]);
#pragma unroll
                for (int j = 0; j < 3; ++j)
                    b2v[j] = *reinterpret_cast<const bf16x8*>(
                        &Vp[(wcD + j * 16 + l16) * 136 + kc * 32 + quad * 8]);
#pragma unroll
                for (int i = 0; i < 4; ++i)
#pragma unroll
                    for (int j = 0; j < 3; ++j)
                        acc2[i][j] = __builtin_amdgcn_mfma_f32_16x16x32_bf16(
                            a2[i], b2v[j], acc2[i][j], 0, 0, 0);
            }
#pragma unroll
            for (int i = 0; i < 4; ++i)
#pragma unroll
                for (int j = 0; j < 3; ++j) {
                    const int d = wcD + j * 16 + l16;
#pragma unroll
                    for (int r = 0; r < 4; ++r) {
                        const int m = m0 + wrM + i * 16 + quad * 4 + r;
                        opep[(long)b * MPRO * INNER + (long)m * INNER + h * 96 + d]
                            = f2b(acc2[i][j][r]);
                    }
                }
            __syncthreads();   // protect AttT before next own-chunk restage
        }
    }

    // PV1 epilogue
#pragma unroll
    for (int i = 0; i < 2; ++i)
#pragma unroll
        for (int j = 0; j < 3; ++j) {
            const int d = wcD + j * 16 + l16;
#pragma unroll
            for (int r = 0; r < 4; ++r) {
                const int n = nh * 64 + wrN + i * 16 + quad * 4 + r;
                opp[((long)b * NPEP + n) * INNER + h * 96 + d] = f2b(acc1[i][j][r]);
            }
        }
}

// ---------------------------------------------------------------------------
__global__ __launch_bounds__(256) void conv2_kernel(
    const float* __restrict__ pro, const float* __restrict__ pep,
    unsigned short* __restrict__ pro16, unsigned short* __restrict__ pep16,
    int nPro4, int nPep4)
{
    const int i = blockIdx.x * 256 + threadIdx.x;
    const float* in; unsigned short* out; int idx;
    if (i < nPro4) { in = pro; out = pro16; idx = i; }
    else { idx = i - nPro4; if (idx >= nPep4) return; in = pep; out = pep16; }
    float4 v = reinterpret_cast<const float4*>(in)[idx];
    ushort4 o;
    o.x = f2b(v.x); o.y = f2b(v.y); o.z = f2b(v.z); o.w = f2b(v.w);
    reinterpret_cast<ushort4*>(out)[idx] = o;
}

__global__ __launch_bounds__(256) void wtrans_kernel(
    const float* w0, const float* w1, const float* w2,
    const float* w3, const float* w4, const float* w5,
    unsigned short* o0, unsigned short* o1, unsigned short* o2,
    unsigned short* o3, unsigned short* o4, unsigned short* o5)
{
    const float* in; unsigned short* out;
    switch (blockIdx.z) {
        case 0: in = w0; out = o0; break;
        case 1: in = w1; out = o1; break;
        case 2: in = w2; out = o2; break;
        case 3: in = w3; out = o3; break;
        case 4: in = w4; out = o4; break;
        default: in = w5; out = o5; break;
    }
    __shared__ unsigned short t[32][33];
    const int bx = blockIdx.x * 32, by = blockIdx.y * 32;
    const int x = threadIdx.x, y = threadIdx.y;
#pragma unroll
    for (int i = 0; i < 32; i += 8)
        t[y + i][x] = f2b(in[(long)(by + y + i) * 768 + bx + x]);
    __syncthreads();
#pragma unroll
    for (int i = 0; i < 32; i += 8)
        out[(long)(bx + y + i) * 768 + by + x] = t[x][y + i];
}

// row softmax over 2048 bf16 scores, with masking folded in.
__global__ __launch_bounds__(256) void softmax_kernel(
    unsigned short* __restrict__ s16, float* __restrict__ attn,
    const int* __restrict__ pepm, const int* __restrict__ prom)
{
    __shared__ float smx[4], sms[4];
    const long row = blockIdx.x;
    const int b = (int)(row >> 10);
    const int n = (int)(row & 127);
    unsigned short* p16 = s16 + row * (long)MPRO;
    float* pf = attn + row * (long)MPRO;
    const int tid = threadIdx.x;
    const int wv = tid >> 6;
    const int rowOk = pepm[(b << 7) + n];        // block-uniform

    float v[8];
    float mx = -3.4e38f;
    if (rowOk) {
#pragma unroll
        for (int k = 0; k < 8; ++k) {
            const int c = tid + k * 256;
            float x = b2f(p16[c]);
            if (prom[(b << 11) + c] == 0) x = NEGF;
            v[k] = x; mx = fmaxf(mx, x);
        }
    } else {
#pragma unroll
        for (int k = 0; k < 8; ++k) v[k] = NEGF;
        mx = NEGF;
    }
#pragma unroll
    for (int off = 32; off > 0; off >>= 1) mx = fmaxf(mx, __shfl_xor(mx, off));
    if ((tid & 63) == 0) smx[wv] = mx;
    __syncthreads();
    mx = fmaxf(fmaxf(smx[0], smx[1]), fmaxf(smx[2], smx[3]));

    float sum = 0.f;
#pragma unroll
    for (int k = 0; k < 8; ++k) { v[k] = __expf(v[k] - mx); sum += v[k]; }
#pragma unroll
    for (int off = 32; off > 0; off >>= 1) sum += __shfl_xor(sum, off);
    if ((tid & 63) == 0) sms[wv] = sum;
    __syncthreads();
    const float inv = 1.0f / (sms[0] + sms[1] + sms[2] + sms[3]);
#pragma unroll
    for (int k = 0; k < 8; ++k) {
        const float o = v[k] * inv;
        pf[tid + k * 256] = o;
        p16[tid + k * 256] = f2b(o);
    }
}

// out = LN(b2f(tmp) + bias + res) * g + b, rows of 768
__global__ __launch_bounds__(256) void bias_res_ln(
    const unsigned short* __restrict__ tmp, const float* __restrict__ bias,
    const float* __restrict__ res, const float* __restrict__ gam,
    const float* __restrict__ bet, float* __restrict__ out)
{
    __shared__ float red[8];
    const long row = blockIdx.x;
    const unsigned short* t = tmp + row * INNER;
    const float* r = res + row * INNER;
    float* o = out + row * INNER;
    const int tid = threadIdx.x;
    const int wv = tid >> 6;

    float v[3]; float s = 0.f;
#pragma unroll
    for (int k = 0; k < 3; ++k) { const int c = tid + k * 256; v[k] = b2f(t[c]) + bias[c] + r[c]; s += v[k]; }
#pragma unroll
    for (int off = 32; off > 0; off >>= 1) s += __shfl_xor(s, off);
    if ((tid & 63) == 0) red[wv] = s;
    __syncthreads();
    const float mu = (red[0] + red[1] + red[2] + red[3]) * (1.0f / INNER);

    float vs = 0.f;
#pragma unroll
    for (int k = 0; k < 3; ++k) { const float d = v[k] - mu; vs += d * d; }
#pragma unroll
    for (int off = 32; off > 0; off >>= 1) vs += __shfl_xor(vs, off);
    if ((tid & 63) == 0) red[4 + wv] = vs;
    __syncthreads();
    const float rstd = rsqrtf((red[4] + red[5] + red[6] + red[7]) * (1.0f / INNER) + LN_EPS);
#pragma unroll
    for (int k = 0; k < 3; ++k) { const int c = tid + k * 256; o[c] = (v[k] - mu) * rstd * gam[c] + bet[c]; }
}

// ---------------------------------------------------------------------------
extern "C" void kernel_launch(void* const* d_in, const int* in_sizes, int n_in,
                              void* d_out, int out_size, void* d_ws, size_t ws_size,
                              hipStream_t stream)
{
    (void)in_sizes; (void)n_in; (void)out_size; (void)ws_size;

    const float* peptide = (const float*)d_in[0];
    const float* protein = (const float*)d_in[1];
    const int*   pepm    = (const int*)  d_in[2];
    const int*   prom    = (const int*)  d_in[3];
    const float* Wq      = (const float*)d_in[4];
    const float* Wk      = (const float*)d_in[5];
    const float* Wv_prot = (const float*)d_in[6];
    const float* Wv_pep  = (const float*)d_in[7];
    const float* Wo_prot = (const float*)d_in[8];
    const float* bo_prot = (const float*)d_in[9];
    const float* Wo_pep  = (const float*)d_in[10];
    const float* bo_pep  = (const float*)d_in[11];
    const float* ln_g    = (const float*)d_in[12];
    const float* ln_b    = (const float*)d_in[13];

    // --- workspace layout (byte offsets, aliased) ---
    char* ws = (char*)d_ws;
    auto U = [&](size_t off) { return (unsigned short*)(ws + off); };
    unsigned short* WT0   = U(0);             // 6 x 1179648, live throughout
    unsigned short* WT1   = U(1179648);
    unsigned short* WT2   = U(2 * 1179648);
    unsigned short* WT3   = U(3 * 1179648);
    unsigned short* WT4   = U(4 * 1179648);
    unsigned short* WT5   = U(5 * 1179648);
    unsigned short* q16   = U(7077888);       // 3145728   [projQ, scores]
    unsigned short* k16   = U(10223616);      // 50331648  [projK, scores]
    unsigned short* vpT   = U(60555264);      // 50331648  [projVprot, fusedpv]
    unsigned short* vpepT = U(110886912);     // 3145728   [projVpep, fusedpv]
    unsigned short* s16   = U(114032640);     // 67108864  [scores..fusedpv] (attn16 in place)
    unsigned short* pro16 = U(114032640);     // 50331648  [conv, proj] (pre-scores)
    unsigned short* pep16 = U(164364288);     // 3145728   [conv, proj]  (pre-scores)
    unsigned short* opp   = U(7077888);       // 3145728   [fusedpv, O1] over dead q16
    unsigned short* opep  = U(10223616);      // 50331648  [fusedpv, O2] over dead k16 (exact fit)
    unsigned short* tmp1  = U(164364288);     // 3145728   [O1, LN1]  over dead pep16
    unsigned short* tmp2  = U(63700992);      // 50331648  [O2, LN2]  over dead vpT tail/vpepT

    float* outP = (float*)d_out;                  // (16,128,768)
    float* outQ = outP + 16 * 128 * 768;          // (16,2048,768)
    float* attn = outQ + (long)16 * 2048 * 768;   // (16,8,128,2048) fp32

    // 1. bf16 conversions + weight transposes
    conv2_kernel<<<26112, 256, 0, stream>>>(protein, peptide, pro16, pep16, 6291456, 393216);
    wtrans_kernel<<<dim3(24, 24, 6), dim3(32, 8), 0, stream>>>(
        Wq, Wk, Wv_prot, Wv_pep, Wo_prot, Wo_pep, WT0, WT1, WT2, WT3, WT4, WT5);

    // 2. merged projections (direct-global GEMM):
    //    pep -> {q16 (M3 layout), vpepT (M4)}; pro -> {k16, vpT}
    gemm_dg<128, 5><<<dim3(12, 16, 1), 256, 0, stream>>>(
        pep16, WT0, q16, 768, 768, 768, 768, 0,
        0, 0, 0, 0, 0, 0, 7, 0, WT3, vpepT);
    gemm_dg<128, 5><<<dim3(3072, 1, 1), 256, 0, stream>>>(
        pro16, WT1, k16, 768, 768, 768, 768, 0,
        0, 0, 0, 0, 0, 0, 11, 12, WT2, vpT);

    // 3. scores = scale * q.k -> bf16 (mask applied in softmax)
    gemm_dg<128, 1><<<dim3(16, 1, 128), 256, 0, stream>>>(
        q16, k16, s16, 2048, 96, 96, 96, 2048,
        98304L, 12288L, 1572864L, 196608L, 2097152L, 262144L, 0, 0, nullptr, nullptr);

    // 4. softmax (masked): fp32 attn to d_out + bf16 in place
    softmax_kernel<<<16384, 256, 0, stream>>>(s16, attn, pepm, prom);

    // 5. fused PV1 + PV2
    fusedpv_kernel<<<256, 256, 0, stream>>>(s16, vpT, vpepT, opp, opep);

    // 6. O1 + LN1
    gemm_dg<64, 2><<<dim3(6, 32, 1), 256, 0, stream>>>(
        opp, WT4, tmp1, 768, 768, 768, 768, 768,
        0, 0, 0, 0, 0, 0, 0, 0, nullptr, nullptr);
    bias_res_ln<<<2048, 256, 0, stream>>>(tmp1, bo_prot, peptide, ln_g, ln_b, outP);

    // 7. O2 + LN2
    gemm_dg<128, 2><<<dim3(1536, 1, 1), 256, 0, stream>>>(
        opep, WT5, tmp2, 768, 768, 768, 768, 768,
        0, 0, 0, 0, 0, 0, 0, 6, nullptr, nullptr);
    bias_res_ln<<<32768, 256, 0, stream>>>(tmp2, bo_pep, protein, ln_g, ln_b, outQ);
}

// Round 9
// 738.233 us; speedup vs baseline: 1.3723x; 1.3723x over previous
//
#include <hip/hip_runtime.h>
#include <math.h>

static constexpr int HEADS  = 8;
static constexpr int DHEAD  = 96;
static constexpr int INNER  = 768;
static constexpr int NPEP   = 128;
static constexpr int MPRO   = 2048;
static constexpr float ATT_SCALE = 0.10206207261596577f;  // 96^-0.5
static constexpr float NEGF   = -1000000.0f;
static constexpr float LN_EPS = 1e-5f;

typedef __attribute__((ext_vector_type(8))) short bf16x8;
typedef __attribute__((ext_vector_type(4))) float f32x4;

__device__ __forceinline__ unsigned short f2b(float f) {
    unsigned u = __builtin_bit_cast(unsigned, f);
    u += 0x7fffu + ((u >> 16) & 1u);          // RNE
    return (unsigned short)(u >> 16);
}
__device__ __forceinline__ float b2f(unsigned short u) {
    return __builtin_bit_cast(float, (unsigned)u << 16);
}

__device__ __forceinline__ void async16(const unsigned short* g, unsigned short* l) {
    __builtin_amdgcn_global_load_lds(
        (const __attribute__((address_space(1))) void*)g,
        (__attribute__((address_space(3))) void*)l, 16, 0, 0);
}

// ---------------------------------------------------------------------------
// BK=64 bf16 MFMA GEMM (B^T form), BM=BN=128, 4 waves, double-buffered 64 KB
// LDS, counted-vmcnt pipeline (R7 best-measured config: 160 us on the big
// projection; the LDS-staged family ceiling at K=768 per the 8-round
// ablation matrix).
// Swizzle (row pitch 128B): store granule g from source col g^(row&7);
// read granule (kc*4+quad)^(r&7).
// MODE 2: row-major bf16 out.
// MODE 5: merged dual projection (virtual N=1536): n0<768 -> B->C head-split
//         (b,h,len,96); n0>=768 -> B2->C2 (b,h,96,len). Block-uniform.
// MODE 6: merged O1+O2: contiguous A rows; m0<2048 -> weights B, else B2;
//         single row-major C (block-uniform, m-tiles never straddle).
// Grid 1-D, XCD-chunked bijective swizzle (grid%8==0), nx col-tiles.
// ---------------------------------------------------------------------------
template<int MODE>
__global__ __launch_bounds__(256) void gemm_k64(
    const unsigned short* __restrict__ A, const unsigned short* __restrict__ B,
    unsigned short* __restrict__ C,
    int N, int K, int lda, int ldb, int ldc,
    int lenShift, int nx,
    const unsigned short* __restrict__ B2, unsigned short* __restrict__ C2)
{
    __shared__ unsigned short As[2][128 * 64];
    __shared__ unsigned short Bs[2][128 * 64];

    const int tid = threadIdx.x;
    const int bid = blockIdx.x;
    const int per = gridDim.x >> 3;              // grid % 8 == 0 (bijective)
    const int v   = (bid & 7) * per + (bid >> 3);
    int n0        = (v % nx) * 128;
    const int m0  = (v / nx) * 128;

    bool sideB = false;
    if (MODE == 5 && n0 >= 768) { sideB = true; n0 -= 768; }
    const unsigned short* Bb;
    if (MODE == 6)      Bb = (m0 >= 2048) ? B2 : B;   // O1 rows < 2048, else O2
    else                Bb = (MODE == 5 && sideB) ? B2 : B;

    const int l = tid & 63, w = tid >> 6;
    const int sRowBase = w * 8 + ((tid >> 3) & 7);   // + ro*32 per round
    const int sG = tid & 7;                          // LDS granule (linear dest)

    const int lane = tid & 63;
    const int l16  = lane & 15;
    const int quad = lane >> 4;
    const int wr   = (w >> 1) * 64;
    const int wc   = (w & 1) * 64;

    f32x4 acc[4][4];
#pragma unroll
    for (int i = 0; i < 4; ++i)
#pragma unroll
        for (int j = 0; j < 4; ++j) acc[i][j] = (f32x4){0.f, 0.f, 0.f, 0.f};

    // stage K-tile t (64 cols) into buffer bi: 4 rounds x (1 A + 1 B) = 8 loads
    auto stageT = [&](int t, int bi) {
        const int k0 = t << 6;
#pragma unroll
        for (int ro = 0; ro < 4; ++ro) {
            const int row = ro * 32 + sRowBase;
            const int col = k0 + ((sG ^ (row & 7)) * 8);   // pre-swizzled source
            unsigned short* dst = &As[bi][ro * 2048 + w * 512 + l * 8];
            async16(A + (long)(m0 + row) * lda + col, dst);
            int br = n0 + row; if (br > N - 1) br = N - 1;
            unsigned short* dstB = &Bs[bi][ro * 2048 + w * 512 + l * 8];
            async16(Bb + (long)br * ldb + col, dstB);
        }
    };

    const int NT = K >> 6;
    stageT(0, 0);
    stageT(1, 1);

    int bi = 0;
    for (int t = 0; t < NT; ++t) {
        if (t < NT - 1) asm volatile("s_waitcnt vmcnt(8)" ::: "memory");
        else            asm volatile("s_waitcnt vmcnt(0)" ::: "memory");
        __builtin_amdgcn_s_barrier();

#pragma unroll
        for (int kc = 0; kc < 2; ++kc) {
            bf16x8 af[4], bfr[4];
#pragma unroll
            for (int i = 0; i < 4; ++i) {
                const int rA = wr + i * 16 + l16;
                af[i] = *reinterpret_cast<const bf16x8*>(
                    &As[bi][rA * 64 + (((kc * 4 + quad) ^ (rA & 7)) * 8)]);
            }
#pragma unroll
            for (int j = 0; j < 4; ++j) {
                const int rB = wc + j * 16 + l16;
                bfr[j] = *reinterpret_cast<const bf16x8*>(
                    &Bs[bi][rB * 64 + (((kc * 4 + quad) ^ (rB & 7)) * 8)]);
            }
            __builtin_amdgcn_s_setprio(1);
#pragma unroll
            for (int i = 0; i < 4; ++i)
#pragma unroll
                for (int j = 0; j < 4; ++j)
                    acc[i][j] = __builtin_amdgcn_mfma_f32_16x16x32_bf16(af[i], bfr[j], acc[i][j], 0, 0, 0);
            __builtin_amdgcn_s_setprio(0);
        }

        __builtin_amdgcn_s_barrier();            // all waves done reading buf bi
        __builtin_amdgcn_sched_barrier(0);       // pin: no hoist across barrier
        if (t + 2 < NT) stageT(t + 2, bi);       // refill just-freed buffer
        bi ^= 1;
    }

#pragma unroll
    for (int i = 0; i < 4; ++i) {
#pragma unroll
        for (int j = 0; j < 4; ++j) {
            const int col = n0 + wc + j * 16 + l16;
            if ((MODE == 2 || MODE == 6) && col >= N) continue;
            const int h = col / 96, d = col - h * 96;
#pragma unroll
            for (int r = 0; r < 4; ++r) {
                const int row = m0 + wr + i * 16 + quad * 4 + r;
                float val = acc[i][j][r];
                if (MODE == 2 || MODE == 6) {
                    C[(long)row * ldc + col] = f2b(val);
                } else { // MODE 5
                    const int bb = row >> lenShift, rr = row & ((1 << lenShift) - 1);
                    if (!sideB)
                        C [(((long)(bb * 8 + h) << lenShift) + rr) * 96 + d] = f2b(val);
                    else
                        C2[(((long)(bb * 8 + h) * 96 + d) << lenShift) + rr] = f2b(val);
                }
            }
        }
    }
}

// ---------------------------------------------------------------------------
// BK=32 bf16 MFMA GEMM (PIPE=2 counted-vmcnt, R6-proven) - scores (K=96, z).
// ---------------------------------------------------------------------------
template<int TM, int MODE>
__global__ __launch_bounds__(256) void gemm_bf16(
    const unsigned short* __restrict__ A, const unsigned short* __restrict__ B,
    unsigned short* __restrict__ C,
    int M, int N, int K, int lda, int ldb, int ldc,
    long sAb, long sAh, long sBb, long sBh, long sCb, long sCh,
    int lenShift, int nxSwz,
    const unsigned short* __restrict__ B2, unsigned short* __restrict__ C2)
{
    (void)M; (void)lenShift; (void)B2; (void)C2; (void)nxSwz;
    constexpr int FR   = TM / 32;               // row-fragments per wave
    constexpr int PIPE = 2;
    __shared__ unsigned short As[PIPE][TM * 32];
    __shared__ unsigned short Bs[PIPE][128 * 32];

    const int tid = threadIdx.x;
    const int bx = blockIdx.x, by = blockIdx.y;
    const int n0  = bx * 128;
    const int m0  = by * TM;
    const int z   = blockIdx.z;
    const int zb  = z >> 3, zh = z & 7;

    const unsigned short* Ab = A + zb * sAb + zh * sAh;
    const unsigned short* Bb = B + zb * sBb + zh * sBh;

    const int rS = tid >> 2;
    const int kS = (((tid & 3) ^ ((rS >> 1) & 3)) * 8);  // swizzled source granule
    const int wave = tid >> 6;

    const int lane = tid & 63;
    const int l16  = lane & 15;
    const int quad = lane >> 4;
    const int wr   = (wave >> 1) * (TM / 2);
    const int wc   = (wave & 1) * 64;

    f32x4 acc[FR][4];
#pragma unroll
    for (int i = 0; i < FR; ++i)
#pragma unroll
        for (int j = 0; j < 4; ++j) acc[i][j] = (f32x4){0.f, 0.f, 0.f, 0.f};

    auto stageT = [&](int t, int bi) {
        const int k0 = t << 5;
        unsigned short* a0 = &As[bi][wave * 512];
        async16(Ab + (long)(m0 + rS) * lda + k0 + kS, a0);
        if (TM == 128)
            async16(Ab + (long)(m0 + 64 + rS) * lda + k0 + kS, a0 + 2048);
        int bR0 = n0 + rS;      if (bR0 > N - 1) bR0 = N - 1;
        int bR1 = n0 + 64 + rS; if (bR1 > N - 1) bR1 = N - 1;
        unsigned short* b0 = &Bs[bi][wave * 512];
        async16(Bb + (long)bR0 * ldb + k0 + kS, b0);
        async16(Bb + (long)bR1 * ldb + k0 + kS, b0 + 2048);
    };

    const int NT = K >> 5;
    stageT(0, 0);
    if (NT > 1) stageT(1, 1);

    int bi = 0;
    for (int t = 0; t < NT; ++t) {
        if (t < NT - 1) {
            if constexpr (TM == 128) asm volatile("s_waitcnt vmcnt(4)" ::: "memory");
            else                     asm volatile("s_waitcnt vmcnt(3)" ::: "memory");
        } else {
            asm volatile("s_waitcnt vmcnt(0)" ::: "memory");
        }
        __builtin_amdgcn_s_barrier();

        bf16x8 af[FR], bfr[4];
#pragma unroll
        for (int i = 0; i < FR; ++i) {
            const int rA = wr + i * 16 + l16;
            af[i] = *reinterpret_cast<const bf16x8*>(
                &As[bi][rA * 32 + ((quad ^ ((rA >> 1) & 3)) * 8)]);
        }
#pragma unroll
        for (int j = 0; j < 4; ++j) {
            const int rB = wc + j * 16 + l16;
            bfr[j] = *reinterpret_cast<const bf16x8*>(
                &Bs[bi][rB * 32 + ((quad ^ ((rB >> 1) & 3)) * 8)]);
        }

        __builtin_amdgcn_s_setprio(1);
#pragma unroll
        for (int i = 0; i < FR; ++i)
#pragma unroll
            for (int j = 0; j < 4; ++j)
                acc[i][j] = __builtin_amdgcn_mfma_f32_16x16x32_bf16(af[i], bfr[j], acc[i][j], 0, 0, 0);
        __builtin_amdgcn_s_setprio(0);

        __builtin_amdgcn_s_barrier();
        __builtin_amdgcn_sched_barrier(0);
        if (t + PIPE < NT) stageT(t + PIPE, bi);
        bi ^= 1;
    }

#pragma unroll
    for (int i = 0; i < FR; ++i) {
#pragma unroll
        for (int j = 0; j < 4; ++j) {
            const int col = n0 + wc + j * 16 + l16;
#pragma unroll
            for (int r = 0; r < 4; ++r) {
                const int row = m0 + wr + i * 16 + quad * 4 + r;
                float v = acc[i][j][r];
                if (MODE == 1) {
                    v *= ATT_SCALE;
                    C[zb * sCb + zh * sCh + (long)row * ldc + col] = f2b(v);
                } else {
                    C[zb * sCb + zh * sCh + (long)row * ldc + col] = f2b(v);
                }
            }
        }
    }
}

// ---------------------------------------------------------------------------
// Fused PV: one block per (z, nh) with z = b*8+h, nh in {0,1}; 256 blocks.
//   PV1: opp[b,n,h*96+d] = sum_m attn[z,n,m]*vpT[z,d,m]   (direct-global frags)
//   PV2: opep[b,m,h*96+d] = sum_n attn[z,n,m]*vpepT[z,d,n] (LDS transpose)
// ---------------------------------------------------------------------------
__global__ __launch_bounds__(256) void fusedpv_kernel(
    const unsigned short* __restrict__ attn16,  // (z,128,2048) bf16
    const unsigned short* __restrict__ vprotT,  // (z,96,2048)
    const unsigned short* __restrict__ vpepT,   // (z,96,128)
    unsigned short* __restrict__ opp,           // (b,128,768)
    unsigned short* __restrict__ opep)          // (b,2048,768)
{
    __shared__ unsigned short AttT[128 * 136];  // [m][n] for current chunk
    __shared__ unsigned short Vp[96 * 136];     // [d][n], resident

    const int id = blockIdx.x;
    const int z  = ((id >> 4) << 3) + (id & 7); // ids i, i+8 share z (same XCD)
    const int nh = (id >> 3) & 1;
    const int b  = z >> 3, h = z & 7;

    const unsigned short* Az = attn16 + (long)z * NPEP * MPRO;
    const unsigned short* Vz = vprotT + (long)z * 96 * MPRO;
    const unsigned short* Pz = vpepT  + (long)z * 96 * 128;

    const int tid  = threadIdx.x;
    const int lane = tid & 63;
    const int l16  = lane & 15;
    const int quad = lane >> 4;
    const int wave = tid >> 6;
    const int wrN  = (wave >> 1) * 32;   // PV1 row base within this block's 64
    const int wrM  = (wave >> 1) * 64;   // PV2 row base within 128-chunk
    const int wcD  = (wave & 1) * 48;    // d col base (2 waves x 48 = 96)

    // stage Vp[d][n] (96x128 -> pitch 136): 1536 8-elem chunks, 6/thread
#pragma unroll
    for (int e = 0; e < 6; ++e) {
        const int c = tid + e * 256;
        const int row = c >> 4, coloff = (c & 15) * 8;
        bf16x8 v = *reinterpret_cast<const bf16x8*>(Pz + row * 128 + coloff);
        *reinterpret_cast<bf16x8*>(&Vp[row * 136 + coloff]) = v;
    }
    __syncthreads();

    f32x4 acc1[2][3];
#pragma unroll
    for (int i = 0; i < 2; ++i)
#pragma unroll
        for (int j = 0; j < 3; ++j) acc1[i][j] = (f32x4){0.f, 0.f, 0.f, 0.f};

    for (int cc = 0; cc < 16; ++cc) {
        const int m0 = cc * 128;
        const bool own = (cc >> 3) == nh;        // block-uniform

        // PV1 fragment loads (direct global, issued first to hide latency)
        bf16x8 a1[2][4], b1[3][4];
#pragma unroll
        for (int i = 0; i < 2; ++i) {
            const int n = nh * 64 + wrN + i * 16 + l16;
#pragma unroll
            for (int kc = 0; kc < 4; ++kc)
                a1[i][kc] = *reinterpret_cast<const bf16x8*>(
                    Az + (long)n * MPRO + m0 + kc * 32 + quad * 8);
        }
#pragma unroll
        for (int j = 0; j < 3; ++j) {
            const int d = wcD + j * 16 + l16;
#pragma unroll
            for (int kc = 0; kc < 4; ++kc)
                b1[j][kc] = *reinterpret_cast<const bf16x8*>(
                    Vz + (long)d * MPRO + m0 + kc * 32 + quad * 8);
        }

        if (own) {
            // stage AttT[m][n] = Az[n][m0+m]
            const int mBase = (tid & 7) * 16;
#pragma unroll
            for (int nn = 0; nn < 128; nn += 32) {
                const int n = nn + (tid >> 3);
#pragma unroll
                for (int c = 0; c < 2; ++c) {
                    bf16x8 v = *reinterpret_cast<const bf16x8*>(
                        Az + (long)n * MPRO + m0 + mBase + c * 8);
#pragma unroll
                    for (int jj = 0; jj < 8; ++jj)
                        AttT[(mBase + c * 8 + jj) * 136 + n] = (unsigned short)v[jj];
                }
            }
            __syncthreads();
        }

        // PV1 MFMAs (accumulate across all 16 chunks)
#pragma unroll
        for (int kc = 0; kc < 4; ++kc)
#pragma unroll
            for (int i = 0; i < 2; ++i)
#pragma unroll
                for (int j = 0; j < 3; ++j)
                    acc1[i][j] = __builtin_amdgcn_mfma_f32_16x16x32_bf16(
                        a1[i][kc], b1[j][kc], acc1[i][j], 0, 0, 0);

        if (own) {
            // PV2 for this chunk: K = n = 128, fresh accumulator
            f32x4 acc2[4][3];
#pragma unroll
            for (int i = 0; i < 4; ++i)
#pragma unroll
                for (int j = 0; j < 3; ++j) acc2[i][j] = (f32x4){0.f, 0.f, 0.f, 0.f};
#pragma unroll
            for (int kc = 0; kc < 4; ++kc) {
                bf16x8 a2[4], b2v[3];
#pragma unroll
                for (int i = 0; i < 4; ++i)
                    a2[i] = *reinterpret_cast<const bf16x8*>(
                        &AttT[(wrM + i * 16 + l16) * 136 + kc * 32 + quad * 8]);
#pragma unroll
                for (int j = 0; j < 3; ++j)
                    b2v[j] = *reinterpret_cast<const bf16x8*>(
                        &Vp[(wcD + j * 16 + l16) * 136 + kc * 32 + quad * 8]);
#pragma unroll
                for (int i = 0; i < 4; ++i)
#pragma unroll
                    for (int j = 0; j < 3; ++j)
                        acc2[i][j] = __builtin_amdgcn_mfma_f32_16x16x32_bf16(
                            a2[i], b2v[j], acc2[i][j], 0, 0, 0);
            }
#pragma unroll
            for (int i = 0; i < 4; ++i)
#pragma unroll
                for (int j = 0; j < 3; ++j) {
                    const int d = wcD + j * 16 + l16;
#pragma unroll
                    for (int r = 0; r < 4; ++r) {
                        const int m = m0 + wrM + i * 16 + quad * 4 + r;
                        opep[(long)b * MPRO * INNER + (long)m * INNER + h * 96 + d]
                            = f2b(acc2[i][j][r]);
                    }
                }
            __syncthreads();   // protect AttT before next own-chunk restage
        }
    }

    // PV1 epilogue
#pragma unroll
    for (int i = 0; i < 2; ++i)
#pragma unroll
        for (int j = 0; j < 3; ++j) {
            const int d = wcD + j * 16 + l16;
#pragma unroll
            for (int r = 0; r < 4; ++r) {
                const int n = nh * 64 + wrN + i * 16 + quad * 4 + r;
                opp[((long)b * NPEP + n) * INNER + h * 96 + d] = f2b(acc1[i][j][r]);
            }
        }
}

// ---------------------------------------------------------------------------
__global__ __launch_bounds__(256) void conv2_kernel(
    const float* __restrict__ pro, const float* __restrict__ pep,
    unsigned short* __restrict__ pro16, unsigned short* __restrict__ pep16,
    int nPro4, int nPep4)
{
    const int i = blockIdx.x * 256 + threadIdx.x;
    const float* in; unsigned short* out; int idx;
    if (i < nPro4) { in = pro; out = pro16; idx = i; }
    else { idx = i - nPro4; if (idx >= nPep4) return; in = pep; out = pep16; }
    float4 v = reinterpret_cast<const float4*>(in)[idx];
    ushort4 o;
    o.x = f2b(v.x); o.y = f2b(v.y); o.z = f2b(v.z); o.w = f2b(v.w);
    reinterpret_cast<ushort4*>(out)[idx] = o;
}

__global__ __launch_bounds__(256) void wtrans_kernel(
    const float* w0, const float* w1, const float* w2,
    const float* w3, const float* w4, const float* w5,
    unsigned short* o0, unsigned short* o1, unsigned short* o2,
    unsigned short* o3, unsigned short* o4, unsigned short* o5)
{
    const float* in; unsigned short* out;
    switch (blockIdx.z) {
        case 0: in = w0; out = o0; break;
        case 1: in = w1; out = o1; break;
        case 2: in = w2; out = o2; break;
        case 3: in = w3; out = o3; break;
        case 4: in = w4; out = o4; break;
        default: in = w5; out = o5; break;
    }
    __shared__ unsigned short t[32][33];
    const int bx = blockIdx.x * 32, by = blockIdx.y * 32;
    const int x = threadIdx.x, y = threadIdx.y;
#pragma unroll
    for (int i = 0; i < 32; i += 8)
        t[y + i][x] = f2b(in[(long)(by + y + i) * 768 + bx + x]);
    __syncthreads();
#pragma unroll
    for (int i = 0; i < 32; i += 8)
        out[(long)(bx + y + i) * 768 + by + x] = t[x][y + i];
}

// row softmax over 2048 bf16 scores, with masking folded in.
__global__ __launch_bounds__(256) void softmax_kernel(
    unsigned short* __restrict__ s16, float* __restrict__ attn,
    const int* __restrict__ pepm, const int* __restrict__ prom)
{
    __shared__ float smx[4], sms[4];
    const long row = blockIdx.x;
    const int b = (int)(row >> 10);
    const int n = (int)(row & 127);
    unsigned short* p16 = s16 + row * (long)MPRO;
    float* pf = attn + row * (long)MPRO;
    const int tid = threadIdx.x;
    const int wv = tid >> 6;
    const int rowOk = pepm[(b << 7) + n];        // block-uniform

    float v[8];
    float mx = -3.4e38f;
    if (rowOk) {
#pragma unroll
        for (int k = 0; k < 8; ++k) {
            const int c = tid + k * 256;
            float x = b2f(p16[c]);
            if (prom[(b << 11) + c] == 0) x = NEGF;
            v[k] = x; mx = fmaxf(mx, x);
        }
    } else {
#pragma unroll
        for (int k = 0; k < 8; ++k) v[k] = NEGF;
        mx = NEGF;
    }
#pragma unroll
    for (int off = 32; off > 0; off >>= 1) mx = fmaxf(mx, __shfl_xor(mx, off));
    if ((tid & 63) == 0) smx[wv] = mx;
    __syncthreads();
    mx = fmaxf(fmaxf(smx[0], smx[1]), fmaxf(smx[2], smx[3]));

    float sum = 0.f;
#pragma unroll
    for (int k = 0; k < 8; ++k) { v[k] = __expf(v[k] - mx); sum += v[k]; }
#pragma unroll
    for (int off = 32; off > 0; off >>= 1) sum += __shfl_xor(sum, off);
    if ((tid & 63) == 0) sms[wv] = sum;
    __syncthreads();
    const float inv = 1.0f / (sms[0] + sms[1] + sms[2] + sms[3]);
#pragma unroll
    for (int k = 0; k < 8; ++k) {
        const float o = v[k] * inv;
        pf[tid + k * 256] = o;
        p16[tid + k * 256] = f2b(o);
    }
}

// Combined LN for contiguous tmp rows: row<2048 -> peptide-side (outP),
// else protein-side (outQ). out = LN(b2f(tmp)+bias+res)*g + b, rows of 768.
__global__ __launch_bounds__(256) void bias_res_ln2(
    const unsigned short* __restrict__ tmp,
    const float* __restrict__ boP, const float* __restrict__ boQ,
    const float* __restrict__ resP, const float* __restrict__ resQ,
    const float* __restrict__ gam, const float* __restrict__ bet,
    float* __restrict__ outP, float* __restrict__ outQ)
{
    __shared__ float red[8];
    const long row = blockIdx.x;
    const unsigned short* t = tmp + row * INNER;
    const float* bias; const float* r; float* o;
    if (row < 2048) { bias = boP; r = resP + row * INNER; o = outP + row * INNER; }
    else { const long rr = row - 2048; bias = boQ; r = resQ + rr * INNER; o = outQ + rr * INNER; }
    const int tid = threadIdx.x;
    const int wv = tid >> 6;

    float v[3]; float s = 0.f;
#pragma unroll
    for (int k = 0; k < 3; ++k) { const int c = tid + k * 256; v[k] = b2f(t[c]) + bias[c] + r[c]; s += v[k]; }
#pragma unroll
    for (int off = 32; off > 0; off >>= 1) s += __shfl_xor(s, off);
    if ((tid & 63) == 0) red[wv] = s;
    __syncthreads();
    const float mu = (red[0] + red[1] + red[2] + red[3]) * (1.0f / INNER);

    float vs = 0.f;
#pragma unroll
    for (int k = 0; k < 3; ++k) { const float d = v[k] - mu; vs += d * d; }
#pragma unroll
    for (int off = 32; off > 0; off >>= 1) vs += __shfl_xor(vs, off);
    if ((tid & 63) == 0) red[4 + wv] = vs;
    __syncthreads();
    const float rstd = rsqrtf((red[4] + red[5] + red[6] + red[7]) * (1.0f / INNER) + LN_EPS);
#pragma unroll
    for (int k = 0; k < 3; ++k) { const int c = tid + k * 256; o[c] = (v[k] - mu) * rstd * gam[c] + bet[c]; }
}

// ---------------------------------------------------------------------------
extern "C" void kernel_launch(void* const* d_in, const int* in_sizes, int n_in,
                              void* d_out, int out_size, void* d_ws, size_t ws_size,
                              hipStream_t stream)
{
    (void)in_sizes; (void)n_in; (void)out_size; (void)ws_size;

    const float* peptide = (const float*)d_in[0];
    const float* protein = (const float*)d_in[1];
    const int*   pepm    = (const int*)  d_in[2];
    const int*   prom    = (const int*)  d_in[3];
    const float* Wq      = (const float*)d_in[4];
    const float* Wk      = (const float*)d_in[5];
    const float* Wv_prot = (const float*)d_in[6];
    const float* Wv_pep  = (const float*)d_in[7];
    const float* Wo_prot = (const float*)d_in[8];
    const float* bo_prot = (const float*)d_in[9];
    const float* Wo_pep  = (const float*)d_in[10];
    const float* bo_pep  = (const float*)d_in[11];
    const float* ln_g    = (const float*)d_in[12];
    const float* ln_b    = (const float*)d_in[13];

    // --- workspace layout (byte offsets, aliased) ---
    char* ws = (char*)d_ws;
    auto U = [&](size_t off) { return (unsigned short*)(ws + off); };
    unsigned short* WT0   = U(0);             // 6 x 1179648, live throughout
    unsigned short* WT1   = U(1179648);
    unsigned short* WT2   = U(2 * 1179648);
    unsigned short* WT3   = U(3 * 1179648);
    unsigned short* WT4   = U(4 * 1179648);
    unsigned short* WT5   = U(5 * 1179648);
    unsigned short* q16   = U(7077888);       // 3145728   [projQ, scores]
    unsigned short* k16   = U(10223616);      // 50331648  [projK, scores]
    unsigned short* vpT   = U(60555264);      // 50331648  [projVprot, fusedpv]
    unsigned short* vpepT = U(110886912);     // 3145728   [projVpep, fusedpv]
    unsigned short* s16   = U(114032640);     // 67108864  [scores..fusedpv] (attn16 in place)
    unsigned short* pro16 = U(114032640);     // 50331648  [conv, proj] (pre-scores)
    unsigned short* pep16 = U(164364288);     // 3145728   [conv, proj]  (pre-scores)
    unsigned short* opp   = U(7077888);       // 3145728   [fusedpv, O]  over dead q16
    unsigned short* opep  = U(10223616);      // 50331648  [fusedpv, O]  over dead k16
    //   opp|opep are CONTIGUOUS: combined O-GEMM A = U(7077888), 34816x768
    unsigned short* tmpC  = U(60555264);      // 53477376  [O, LN] over dead vpT/+ (34816x768)
    //   rows 0..2047 = O1 (tmp1), rows 2048.. = O2 (tmp2); contiguous for LN2

    float* outP = (float*)d_out;                  // (16,128,768)
    float* outQ = outP + 16 * 128 * 768;          // (16,2048,768)
    float* attn = outQ + (long)16 * 2048 * 768;   // (16,8,128,2048) fp32

    // 1. bf16 conversions + weight transposes
    conv2_kernel<<<26112, 256, 0, stream>>>(protein, peptide, pro16, pep16, 6291456, 393216);
    wtrans_kernel<<<dim3(24, 24, 6), dim3(32, 8), 0, stream>>>(
        Wq, Wk, Wv_prot, Wv_pep, Wo_prot, Wo_pep, WT0, WT1, WT2, WT3, WT4, WT5);

    // 2. merged projections (BK=64 path): pep -> {q16 (M3), vpepT (M4)};
    //    pro -> {k16, vpT}. Grids %8==0, XCD-swizzled.
    gemm_k64<5><<<192, 256, 0, stream>>>(
        pep16, WT0, q16, 768, 768, 768, 768, 0,
        7, 12, WT3, vpepT);
    gemm_k64<5><<<3072, 256, 0, stream>>>(
        pro16, WT1, k16, 768, 768, 768, 768, 0,
        11, 12, WT2, vpT);

    // 3. scores = scale * q.k -> bf16 (mask applied in softmax)
    gemm_bf16<128, 1><<<dim3(16, 1, 128), 256, 0, stream>>>(
        q16, k16, s16, 128, 2048, 96, 96, 96, 2048,
        98304L, 12288L, 1572864L, 196608L, 2097152L, 262144L, 0, 0, nullptr, nullptr);

    // 4. softmax (masked): fp32 attn to d_out + bf16 in place
    softmax_kernel<<<16384, 256, 0, stream>>>(s16, attn, pepm, prom);

    // 5. fused PV1 + PV2  (writes opp then opep; s16/vpT dead afterwards)
    fusedpv_kernel<<<256, 256, 0, stream>>>(s16, vpT, vpepT, opp, opep);

    // 6. merged O1+O2 GEMM: A = opp|opep (34816x768), B = WT4 (rows<2048) /
    //    WT5, C = contiguous tmpC. 272 m-tiles x 6 n-tiles = 1632 blocks.
    gemm_k64<6><<<1632, 256, 0, stream>>>(
        opp, WT4, tmpC, 768, 768, 768, 768, 768,
        0, 6, WT5, nullptr);

    // 7. merged LN1+LN2 over contiguous tmpC rows
    bias_res_ln2<<<34816, 256, 0, stream>>>(
        tmpC, bo_prot, bo_pep, peptide, protein, ln_g, ln_b, outP, outQ);
}